// Round 8
// baseline (4317.734 us; speedup 1.0000x reference)
//
#include <hip/hip_runtime.h>
#include <hip/hip_fp16.h>
#include <math.h>

// DirModelToFace on MI355X — round 22:
//  * r21 (A-side BN fold, pre-split frag-ordered global W, barrier-free K loop)
//    + 64-ROW TILES: grid 375/750 -> 750/1500, 1 rg/wave, acc[8] (~64 VGPR).
//    Rationale: v-gemm grid 375 = 1.5 waves/SIMD — no TLP to hide the dependent
//    load->fold->MFMA chain (the invariant across all null gemm rewrites).
//    r18's 64-row FETCH explosion was its per-block raw-fp32-W HBM re-read;
//    here W is 128KB/layer bf16 frag-ordered and L2-resident, so doubling the
//    grid only doubles L2 (not HBM) W traffic. A-reads unchanged.
//  * Everything else r21-exact (prefold, CSR, spmm, conv1+masksum, final).

#define EPS 1e-5f

typedef float floatx4 __attribute__((ext_vector_type(4)));
typedef short shortx8 __attribute__((ext_vector_type(8)));

__device__ __forceinline__ float eluf(float x) { return x > 0.f ? x : expm1f(x); }
__device__ __forceinline__ float4 elu4(float4 v) {
    v.x = eluf(v.x); v.y = eluf(v.y); v.z = eluf(v.z); v.w = eluf(v.w); return v;
}
__device__ __forceinline__ short f2bf(float x) {  // round-to-nearest-even bf16
    unsigned u = __builtin_bit_cast(unsigned, x);
    u = u + 0x7FFFu + ((u >> 16) & 1u);
    return (short)(u >> 16);
}
__device__ __forceinline__ float bf2f(short h) {
    unsigned u = ((unsigned)(unsigned short)h) << 16;
    return __builtin_bit_cast(float, u);
}
// hi/lo split: rem = x-bf2f(hi) exact in fp32; total err <= ~2^-16|x|
__device__ __forceinline__ void split2(float x, short& hi, short& lo) {
    unsigned u = __builtin_bit_cast(unsigned, x);
    hi = (short)(u >> 16);
    float r = x - bf2f(hi);
    lo = (short)(__builtin_bit_cast(unsigned, r) >> 16);
}

// Pre-split raw W (32 layer slots) into bf16 hi/lo, MFMA-frag order:
// element (k=kb*32+kq*8+j, c=ct*16+m) at [((kb*8+ct)*64 + kq*16+m)*8 + j].
__global__ void prefold_kernel(const float* __restrict__ rnW, short* __restrict__ Wh,
                               short* __restrict__ Wl) {
    int L = blockIdx.y;
    int id = blockIdx.x * 256 + threadIdx.x;   // 0..4095
    int chunk = id >> 6, lane = id & 63;
    int kb = chunk >> 3, ct = chunk & 7, kq = lane >> 4, m = lane & 15;
    const float* W = rnW + (size_t)L * 32768;
    shortx8 hv, lv;
#pragma unroll
    for (int j = 0; j < 8; ++j) {
        int k = kb * 32 + kq * 8 + j;
        int c = ct * 16 + m;
        float w = W[k * 128 + c];
        short h = f2bf(w);
        hv[j] = h;
        lv[j] = f2bf(w - bf2f(h));
    }
    size_t o = (size_t)L * 32768 + (size_t)id * 8;
    *(shortx8*)&Wh[o] = hv;
    *(shortx8*)&Wl[o] = lv;
}

// v = inputs @ W1 + b1; fp16 shadow; fused elu-stats (A-half of dir0 slot0).
// Blocks >= nConv do the masksum reduction (merged former masksum_kernel).
__global__ void conv1_kernel(const float* __restrict__ in, const float* __restrict__ W1,
                             const float* __restrict__ b1, float* __restrict__ v,
                             __half* __restrict__ vH, int N, float* __restrict__ Sout,
                             const float* __restrict__ mask, float* __restrict__ msum,
                             int nConv) {
    __shared__ float sh[4];
    int t = threadIdx.x;
    if (blockIdx.x >= nConv) {  // masksum for batch b
        int b = blockIdx.x - nConv;
        float s = 0.f;
        for (int n = t; n < N; n += 256) s += mask[(size_t)b * N + n];
        for (int o = 32; o > 0; o >>= 1) s += __shfl_down(s, o);
        if ((t & 63) == 0) sh[t >> 6] = s;
        __syncthreads();
        if (t == 0) msum[b] = sh[0] + sh[1] + sh[2] + sh[3];
        return;
    }
    int c = t & 127, half = t >> 7;
    int r0 = blockIdx.x * 64;
    float w0 = W1[c], w1 = W1[128 + c], w2 = W1[256 + c], bb = b1[c];
    float s1 = 0.f, s2 = 0.f;
    for (int k = 0; k < 32; ++k) {
        int r = r0 + half + 2 * k;
        float x0 = in[r * 3 + 0], x1 = in[r * 3 + 1], x2 = in[r * 3 + 2];
        float val = bb + x0 * w0 + x1 * w1 + x2 * w2;
        v[(size_t)r * 128 + c] = val;
        int b = r / N, vert = r - b * N;
        vH[(size_t)(4 * vert + (c >> 5)) * 128 + b * 32 + (c & 31)] = __float2half(val);
        float e = eluf(val);
        s1 += e; s2 += e * e;
    }
    atomicAdd(&Sout[c], s1);
    atomicAdd(&Sout[256 + c], s2);
}

// ---------------- CSR build (A and D merged via blockIdx.y) ----------------

__global__ void hist2_kernel(const int* __restrict__ rowsA, const int* __restrict__ rowsD,
                             int* __restrict__ cntA, int* __restrict__ cntD) {
    int e = blockIdx.x * 256 + threadIdx.x;
    if (blockIdx.y == 0) atomicAdd(&cntA[rowsA[e]], 1);
    else atomicAdd(&cntD[rowsD[e]], 1);
}

__global__ void partial2_kernel(const int* __restrict__ cntA, const int* __restrict__ cntD,
                                int* __restrict__ partA, int* __restrict__ partD,
                                int RA, int RD) {
    const int* counts = blockIdx.y ? cntD : cntA;
    int* partials = blockIdx.y ? partD : partA;
    int R = blockIdx.y ? RD : RA;
    int t = threadIdx.x;
    int base = blockIdx.x * 1024 + t * 4;
    int s = 0;
#pragma unroll
    for (int j = 0; j < 4; ++j) { int i = base + j; if (i < R) s += counts[i]; }
    __shared__ int sh[256];
    sh[t] = s; __syncthreads();
    for (int st = 128; st > 0; st >>= 1) {
        if (t < st) sh[t] += sh[t + st];
        __syncthreads();
    }
    if (t == 0) partials[blockIdx.x] = sh[0];
}

__global__ void scanp2_kernel(int* __restrict__ partA, int* __restrict__ partD,
                              int* __restrict__ ptrA, int* __restrict__ ptrD,
                              int PA, int PD, int RA, int RD, int total) {
    int* partials = blockIdx.y ? partD : partA;
    int* rowptr = blockIdx.y ? ptrD : ptrA;
    int P = blockIdx.y ? PD : PA;
    int R = blockIdx.y ? RD : RA;
    __shared__ int sh[256];
    int t = threadIdx.x;
    int v = (t < P) ? partials[t] : 0;
    sh[t] = v; __syncthreads();
    for (int st = 1; st < 256; st <<= 1) {
        int tmp = (t >= st) ? sh[t - st] : 0;
        __syncthreads();
        sh[t] += tmp;
        __syncthreads();
    }
    if (t < P) partials[t] = sh[t] - v;
    if (t == 0) rowptr[R] = total;
}

__global__ void apply2_kernel(int* __restrict__ cntA, int* __restrict__ cntD,
                              const int* __restrict__ partA, const int* __restrict__ partD,
                              int* __restrict__ ptrA, int* __restrict__ ptrD,
                              int RA, int RD) {
    int* counts = blockIdx.y ? cntD : cntA;
    const int* partials = blockIdx.y ? partD : partA;
    int* rowptr = blockIdx.y ? ptrD : ptrA;
    int R = blockIdx.y ? RD : RA;
    int t = threadIdx.x;
    int base = blockIdx.x * 1024 + t * 4;
    int c[4]; int s = 0;
#pragma unroll
    for (int j = 0; j < 4; ++j) { int i = base + j; c[j] = (i < R) ? counts[i] : 0; s += c[j]; }
    __shared__ int sh[256];
    sh[t] = s; __syncthreads();
    for (int st = 1; st < 256; st <<= 1) {
        int tmp = (t >= st) ? sh[t - st] : 0;
        __syncthreads();
        sh[t] += tmp;
        __syncthreads();
    }
    int off = partials[blockIdx.x] + sh[t] - s;
#pragma unroll
    for (int j = 0; j < 4; ++j) {
        int i = base + j;
        if (i < R) { rowptr[i] = off; counts[i] = off; }
        off += c[j];
    }
}

__global__ void scatter2_kernel(const int* __restrict__ rowsA, const int* __restrict__ colsA,
                                const float* __restrict__ valsA,
                                const int* __restrict__ rowsD, const int* __restrict__ colsD,
                                const float* __restrict__ valsD,
                                int* __restrict__ fillA, int* __restrict__ fillD,
                                int2* __restrict__ edgesA, int2* __restrict__ edgesD) {
    int e = blockIdx.x * 256 + threadIdx.x;
    if (blockIdx.y == 0) {
        int p = atomicAdd(&fillA[rowsA[e]], 1);
        edgesA[p] = make_int2(colsA[e], __float_as_int(valsA[e]));
    } else {
        int p = atomicAdd(&fillD[rowsD[e]], 1);
        edgesD[p] = make_int2(colsD[e], __float_as_int(valsD[e]));
    }
}

// ---- CSR spmm: 16 waves/block, 2 rows/wave, 1 dword gather/edge, fused B stats ----
template <int DIR>
__global__ __launch_bounds__(1024) void spmm_csr_kernel(
    const int* __restrict__ rowptr, const int2* __restrict__ edges,
    const __half2* __restrict__ xH, float* __restrict__ y, int R4,
    float* __restrict__ Sout) {
    int t = threadIdx.x;
    int waveId = blockIdx.x * 16 + (t >> 6);
    int lane = t & 63;
    int b = lane >> 4, cp = lane & 15;
    const __half2* xb = xH + b * 16 + cp;
    size_t rs = (size_t)R4 * 32;
    __shared__ float red[256];
    if (t < 256) red[t] = 0.f;
    __syncthreads();
#pragma unroll
    for (int rr = 0; rr < 2; ++rr) {
        int r = waveId * 2 + rr;
        int e0 = rowptr[r], e1 = rowptr[r + 1];
        float ax = 0.f, ay = 0.f;
        int e = e0;
        for (; e + 4 <= e1; e += 4) {
            int2 E0 = edges[e], E1 = edges[e + 1], E2 = edges[e + 2], E3 = edges[e + 3];
            __half2 g0 = xb[(size_t)E0.x * 64];
            __half2 g1 = xb[(size_t)E1.x * 64];
            __half2 g2 = xb[(size_t)E2.x * 64];
            __half2 g3 = xb[(size_t)E3.x * 64];
            float v0 = __int_as_float(E0.y), v1 = __int_as_float(E1.y);
            float v2 = __int_as_float(E2.y), v3 = __int_as_float(E3.y);
            float2 f0 = __half22float2(g0), f1 = __half22float2(g1);
            float2 f2 = __half22float2(g2), f3 = __half22float2(g3);
            ax += v0 * f0.x; ay += v0 * f0.y;
            ax += v1 * f1.x; ay += v1 * f1.y;
            ax += v2 * f2.x; ay += v2 * f2.y;
            ax += v3 * f3.x; ay += v3 * f3.y;
        }
        for (; e < e1; ++e) {
            int2 E = edges[e];
            __half2 g = xb[(size_t)E.x * 64];
            float v = __int_as_float(E.y);
            float2 f = __half22float2(g);
            ax += v * f.x; ay += v * f.y;
        }
        *(float2*)&y[(size_t)b * rs + (size_t)r * 32 + cp * 2] = make_float2(ax, ay);
        float ea = eluf(ax), eb = eluf(ay);
        float s1a = ea, s2a = ea * ea, s1b = eb, s2b = eb * eb;
        s1a += __shfl_xor(s1a, 16); s1a += __shfl_xor(s1a, 32);
        s2a += __shfl_xor(s2a, 16); s2a += __shfl_xor(s2a, 32);
        s1b += __shfl_xor(s1b, 16); s1b += __shfl_xor(s1b, 32);
        s2b += __shfl_xor(s2b, 16); s2b += __shfl_xor(s2b, 32);
        if (lane < 16) {
            int ch = (r & 3) * 32 + cp * 2;
            atomicAdd(&red[ch], s1a);
            atomicAdd(&red[ch + 1], s1b);
            atomicAdd(&red[128 + ch], s2a);
            atomicAdd(&red[128 + ch + 1], s2b);
        }
    }
    __syncthreads();
    if (t < 128) atomicAdd(&Sout[128 + t], red[t]);
    else if (t < 256) atomicAdd(&Sout[384 + (t - 128)], red[t]);
}

// MFMA GEMM, 64-row tiles, A-side BN fold, frag-ordered global W, no K barriers.
// MODEB: 0 = per-row fp32 B (msg, elu), 1 = broadcast avg, 2 = B zero.
template <int MODEB>
__global__ __launch_bounds__(256) void gemm_mfma(
    const float* __restrict__ A, const float* __restrict__ Bs,
    const float* __restrict__ S, const float* __restrict__ gvec,
    const float* __restrict__ bevec, const short* __restrict__ Wh,
    const short* __restrict__ Wl, const float* __restrict__ bvec,
    const float* __restrict__ resid, float* __restrict__ out,
    __half* __restrict__ shadow, float* __restrict__ Sout,
    const float* __restrict__ mask, float* __restrict__ avgout,
    const float* __restrict__ avgacc, const float* __restrict__ msum,
    float invR, int rowsPerBatch) {
    __shared__ float sS[256];
    __shared__ float sMS[256];
    __shared__ float avgLDS[512];
    __shared__ float red[256];
    __shared__ float redv[256];
    const int t = threadIdx.x;
    const int lane = t & 63;
    const int wave = t >> 6;
    const int rowBase = blockIdx.x * 64 + wave * 16;
    const int m = lane & 15;
    const int kq = lane >> 4;
    const int bBlk = (blockIdx.x * 64) / rowsPerBatch;  // block spans <=2 batches
    const int arow = rowBase + m;

    // ---- per-block BN stats prologue (sS = scale, sMS = shift) ----
    {
        int k = t;
        float mean, var;
        if (MODEB == 1 && k >= 128) {
            int c = k - 128;
            float a0 = avgacc[c] / msum[0];
            float a1 = avgacc[128 + c] / msum[1];
            float a2 = avgacc[256 + c] / msum[2];
            float a3 = avgacc[384 + c] / msum[3];
            avgLDS[c] = a0; avgLDS[128 + c] = a1;
            avgLDS[256 + c] = a2; avgLDS[384 + c] = a3;
            mean = 0.25f * (a0 + a1 + a2 + a3);
            var = 0.25f * (a0 * a0 + a1 * a1 + a2 * a2 + a3 * a3) - mean * mean;
        } else {
            mean = S[k] * invR;
            var = S[256 + k] * invR - mean * mean;
        }
        float s = gvec[k] / sqrtf(var + EPS);
        sS[k] = s;
        sMS[k] = bevec[k] - mean * s;
    }
    __syncthreads();   // the ONLY pre-epilogue barrier

    floatx4 acc[8];
#pragma unroll
    for (int j = 0; j < 8; ++j) acc[j] = {0.f, 0.f, 0.f, 0.f};

#pragma unroll 2
    for (int kb = 0; kb < 8; ++kb) {
        const int k0 = kb * 32 + kq * 8;
        // ---- A' frag: sS*x + sMS, split to hi/lo ----
        shortx8 ah, al;
        {
            float x[8];
            if (kb < 4) {
                float4 p = elu4(*(const float4*)&A[(size_t)arow * 128 + k0]);
                float4 q = elu4(*(const float4*)&A[(size_t)arow * 128 + k0 + 4]);
                x[0] = p.x; x[1] = p.y; x[2] = p.z; x[3] = p.w;
                x[4] = q.x; x[5] = q.y; x[6] = q.z; x[7] = q.w;
            } else if (MODEB == 0) {
                const int kk = k0 - 128;
                float4 p = elu4(*(const float4*)&Bs[(size_t)arow * 128 + kk]);
                float4 q = elu4(*(const float4*)&Bs[(size_t)arow * 128 + kk + 4]);
                x[0] = p.x; x[1] = p.y; x[2] = p.z; x[3] = p.w;
                x[4] = q.x; x[5] = q.y; x[6] = q.z; x[7] = q.w;
            } else if (MODEB == 1) {
                const int kk = k0 - 128;
                const int b = arow / rowsPerBatch;
                float4 p = *(const float4*)&avgLDS[b * 128 + kk];
                float4 q = *(const float4*)&avgLDS[b * 128 + kk + 4];
                x[0] = p.x; x[1] = p.y; x[2] = p.z; x[3] = p.w;
                x[4] = q.x; x[5] = q.y; x[6] = q.z; x[7] = q.w;
            } else {
#pragma unroll
                for (int j = 0; j < 8; ++j) x[j] = 0.f;
            }
#pragma unroll
            for (int j = 0; j < 8; ++j) {
                const int k = k0 + j;
                float ap = sS[k] * x[j] + sMS[k];
                short h, l;
                split2(ap, h, l);
                ah[j] = h;
                al[j] = l;
            }
        }
        // ---- B frags straight from global (frag-ordered, L2-hot) + MFMA ----
#pragma unroll
        for (int ct = 0; ct < 8; ++ct) {
            const size_t wo = ((size_t)(kb * 8 + ct) * 64 + lane) * 8;
            shortx8 bh = *(const shortx8*)&Wh[wo];
            shortx8 bl = *(const shortx8*)&Wl[wo];
            acc[ct] = __builtin_amdgcn_mfma_f32_16x16x32_bf16(ah, bh, acc[ct], 0, 0, 0);
            acc[ct] = __builtin_amdgcn_mfma_f32_16x16x32_bf16(ah, bl, acc[ct], 0, 0, 0);
            acc[ct] = __builtin_amdgcn_mfma_f32_16x16x32_bf16(al, bh, acc[ct], 0, 0, 0);
        }
    }

    // epilogue: C/D layout col=lane&15, row=(lane>>4)*4+reg  [verified m89/m91]
    float mk4[4]; int ib4[4];
    if (avgout) {
#pragma unroll
        for (int r = 0; r < 4; ++r) {
            int row = rowBase + kq * 4 + r;
            mk4[r] = mask[row];
            ib4[r] = (row >= (bBlk + 1) * rowsPerBatch) ? 1 : 0;
        }
    }
    float cs1[8], cs2[8], av0[8], av1[8];
#pragma unroll
    for (int ct = 0; ct < 8; ++ct) { cs1[ct] = 0.f; cs2[ct] = 0.f; av0[ct] = 0.f; av1[ct] = 0.f; }
#pragma unroll
    for (int ct = 0; ct < 8; ++ct) {
        int col = ct * 16 + m;
        float bb = bvec[col];
#pragma unroll
        for (int r = 0; r < 4; ++r) {
            int row = rowBase + kq * 4 + r;
            size_t o = (size_t)row * 128 + col;
            float v = acc[ct][r] + bb;
            if (resid) v += resid[o];
            out[o] = v;
            if (shadow) {
                int b = row / rowsPerBatch, vert = row - b * rowsPerBatch;
                shadow[(size_t)(4 * vert + (col >> 5)) * 128 + b * 32 + (col & 31)] =
                    __float2half(v);
            }
            float e = eluf(v);
            cs1[ct] += e; cs2[ct] += e * e;
            if (avgout) {
                float me = mk4[r] * e;
                if (ib4[r]) av1[ct] += me; else av0[ct] += me;
            }
        }
    }
    if (Sout) {  // fused stats (+ optional avg numerators) for the consuming layer
        __syncthreads();
        red[t] = 0.f;
        if (avgout) redv[t] = 0.f;
        __syncthreads();
#pragma unroll
        for (int ct = 0; ct < 8; ++ct) {
            cs1[ct] += __shfl_xor(cs1[ct], 16); cs1[ct] += __shfl_xor(cs1[ct], 32);
            cs2[ct] += __shfl_xor(cs2[ct], 16); cs2[ct] += __shfl_xor(cs2[ct], 32);
            if (avgout) {
                av0[ct] += __shfl_xor(av0[ct], 16); av0[ct] += __shfl_xor(av0[ct], 32);
                av1[ct] += __shfl_xor(av1[ct], 16); av1[ct] += __shfl_xor(av1[ct], 32);
            }
        }
        if (kq == 0) {
#pragma unroll
            for (int ct = 0; ct < 8; ++ct) {
                atomicAdd(&red[ct * 16 + m], cs1[ct]);
                atomicAdd(&red[128 + ct * 16 + m], cs2[ct]);
                if (avgout) {
                    atomicAdd(&redv[ct * 16 + m], av0[ct]);
                    atomicAdd(&redv[128 + ct * 16 + m], av1[ct]);
                }
            }
        }
        __syncthreads();
        if (t < 128) atomicAdd(&Sout[t], red[t]);
        else atomicAdd(&Sout[256 + (t - 128)], red[t]);
        if (avgout) {
            int plane = t >> 7, col = t & 127;
            int b = bBlk + plane;
            if (b < 4) atomicAdd(&avgout[b * 128 + col], redv[t]);
        }
    }
}

__global__ void fold_final(const float* __restrict__ S, const float* __restrict__ g2,
                           const float* __restrict__ be2, const float* __restrict__ W2,
                           const float* __restrict__ b2, float* __restrict__ W2p, float invR) {
    __shared__ float red[128];
    int c = threadIdx.x;
    float mean = S[c] * invR;
    float var = S[256 + c] * invR - mean * mean;
    float s = g2[c] / sqrtf(var + EPS);
    float w = W2[c];
    W2p[c] = s * w;
    red[c] = (be2[c] - mean * s) * w;
    __syncthreads();
    for (int st = 64; st > 0; st >>= 1) {
        if (c < st) red[c] += red[c + st];
        __syncthreads();
    }
    if (c == 0) W2p[128] = b2[0] + red[0];
}

__global__ void final_out_kernel(const float* __restrict__ f, const float* __restrict__ W2p,
                                 float* __restrict__ out) {
    int t = threadIdx.x;
    int w = t >> 6, lane = t & 63;
    float wa = W2p[lane], wb = W2p[64 + lane], bb = W2p[128];
    int base = blockIdx.x * 16 + w * 4;
#pragma unroll
    for (int rr = 0; rr < 4; ++rr) {
        int row = base + rr;
        float a = eluf(f[(size_t)row * 128 + lane]) * wa +
                  eluf(f[(size_t)row * 128 + 64 + lane]) * wb;
        for (int off = 32; off > 0; off >>= 1) a += __shfl_down(a, off);
        if (lane == 0) out[row] = a + bb;
    }
}

extern "C" void kernel_launch(void* const* d_in, const int* in_sizes, int n_in,
                              void* d_out, int out_size, void* d_ws, size_t ws_size,
                              hipStream_t stream) {
    const float* inputs = (const float*)d_in[0];
    const float* mask = (const float*)d_in[1];
    const int* Di_rows = (const int*)d_in[2];
    const int* Di_cols = (const int*)d_in[3];
    const float* Di_vals = (const float*)d_in[4];
    const int* DiA_rows = (const int*)d_in[5];
    const int* DiA_cols = (const int*)d_in[6];
    const float* DiA_vals = (const float*)d_in[7];
    const float* W1 = (const float*)d_in[8];
    const float* b1 = (const float*)d_in[9];
    const float* rn_gamma = (const float*)d_in[10];
    const float* rn_beta = (const float*)d_in[11];
    const float* rn_W = (const float*)d_in[12];
    const float* rn_b = (const float*)d_in[13];
    const float* g2 = (const float*)d_in[14];
    const float* be2 = (const float*)d_in[15];
    const float* W2 = (const float*)d_in[16];
    const float* b2 = (const float*)d_in[17];
    float* out = (float*)d_out;

    const int B = 4;
    const int BN = in_sizes[1];      // 48000
    const int N = BN / B;            // 12000
    const int BF = out_size;         // 96000
    const int Fn = BF / B;           // 24000
    const int nnz = in_sizes[2];     // 1,152,000
    const int RA = 4 * N;            // 48000
    const int RD = 4 * Fn;           // 96000

    float* ws = (float*)d_ws;
    size_t off = 0;
    float* vA = ws + off;  off += (size_t)BN * 128;
    float* fA = ws + off;  off += (size_t)BF * 128;
    float* msg = ws + off; off += (size_t)BF * 128;   // fp32 spmm out
    __half* vH = (__half*)(ws + off); off += (size_t)RA * 128 / 2;  // [r4][b][32] fp16
    __half* fH = (__half*)(ws + off); off += (size_t)RD * 128 / 2;
    int* ptrA    = (int*)(ws + off);  off += (size_t)RA + 4;
    int2* edgesA = (int2*)(ws + off); off += (size_t)nnz * 2;
    int* ptrD    = (int*)(ws + off);  off += (size_t)RD + 4;
    int2* edgesD = (int2*)(ws + off); off += (size_t)nnz * 2;
    int* cntA    = (int*)(ws + off);  off += (size_t)RA;
    int* cntD    = (int*)(ws + off);  off += (size_t)RD;
    int* partA   = (int*)(ws + off);  off += 256;
    int* partD   = (int*)(ws + off);  off += 256;
    float* Sarena = ws + off; off += 33 * 512;   // pre-zeroed stats slots (2i+j map)
    float* Aarena = ws + off; off += 16 * 512;   // pre-zeroed avg-numerator slots
    float* msum = ws + off;   off += 4;
    float* W2p = ws + off; off += 132;
    short* Wh = (short*)(ws + off); off += (size_t)32 * 32768 / 2;  // pre-split W hi
    short* Wl = (short*)(ws + off); off += (size_t)32 * 32768 / 2;  // pre-split W lo

    const int eBlocks = nnz / 256;
    const int PA = (RA + 1023) / 1024;
    const int PD = (RD + 1023) / 1024;

    hipMemsetAsync(Sarena, 0, (33 * 512 + 16 * 512) * 4, stream);
    hipMemsetAsync(fA, 0, (size_t)BF * 128 * 4, stream);
    hipMemsetAsync(cntA, 0, (size_t)(RA + RD) * 4, stream);  // cntA+cntD contiguous

    // pre-split all 32 layer weight slots into MFMA-frag bf16 hi/lo (once)
    prefold_kernel<<<dim3(16, 32), 256, 0, stream>>>(rn_W, Wh, Wl);

    // ---- build CSR for DiA and Di in one merged chain ----
    hist2_kernel<<<dim3(eBlocks, 2), 256, 0, stream>>>(DiA_rows, Di_rows, cntA, cntD);
    partial2_kernel<<<dim3(PD, 2), 256, 0, stream>>>(cntA, cntD, partA, partD, RA, RD);
    scanp2_kernel<<<dim3(1, 2), 256, 0, stream>>>(partA, partD, ptrA, ptrD, PA, PD,
                                                  RA, RD, nnz);
    apply2_kernel<<<dim3(PD, 2), 256, 0, stream>>>(cntA, cntD, partA, partD, ptrA, ptrD,
                                                   RA, RD);
    scatter2_kernel<<<dim3(eBlocks, 2), 256, 0, stream>>>(DiA_rows, DiA_cols, DiA_vals,
                                                          Di_rows, Di_cols, Di_vals,
                                                          cntA, cntD, edgesA, edgesD);

    // S slot map: conv layer (i,j) -> Sarena + 512*(2i+j); final conv -> slot 32.
    auto slot = [&](int i, int j) { return Sarena + 512 * (2 * i + j); };
    float* Sfinal = Sarena + 512 * 32;

    // conv1 + masksum merged (last B blocks do masksum)
    conv1_kernel<<<BN / 64 + B, 256, 0, stream>>>(inputs, W1, b1, vA, vH, N, slot(0, 0),
                                                  mask, msum, BN / 64);

    auto WhL = [&](int i, int j) { return Wh + (size_t)(i * 2 + j) * 32768; };
    auto WlL = [&](int i, int j) { return Wl + (size_t)(i * 2 + j) * 32768; };

    for (int i = 0; i < 15; ++i) {   // layer 15 (avg) is dead: output depends only on f
        if ((i & 1) == 0) {
            const float* g0 = rn_gamma + (size_t)(i * 2 + 0) * 256;
            const float* be0 = rn_beta + (size_t)(i * 2 + 0) * 256;
            const float* bl0 = rn_b + (size_t)(i * 2 + 0) * 128;
            const float* g1 = rn_gamma + (size_t)(i * 2 + 1) * 256;
            const float* be1 = rn_beta + (size_t)(i * 2 + 1) * 256;
            const float* bl1 = rn_b + (size_t)(i * 2 + 1) * 128;
            float* SoutV = (i < 14) ? slot(i + 1, 0) : nullptr;
            float* avgV = (i < 14) ? (Aarena + 512 * i) : nullptr;

            if (i == 0) {
                // f == 0 -> msg_v == 0 exactly: skip spmm; slot(0,0) B-half stays 0.
                gemm_mfma<2><<<BN / 64, 256, 0, stream>>>(vA, nullptr, slot(0, 0), g0, be0,
                                                          WhL(i, 0), WlL(i, 0), bl0, vA, vA,
                                                          vH, SoutV, mask, avgV, nullptr,
                                                          nullptr, 1.f / BN, N);
            } else {
                spmm_csr_kernel<0><<<RA / 32, 1024, 0, stream>>>(ptrA, edgesA,
                                                                 (const __half2*)fH, msg,
                                                                 RA, slot(i, 0));
                gemm_mfma<0><<<BN / 64, 256, 0, stream>>>(vA, msg, slot(i, 0), g0, be0,
                                                          WhL(i, 0), WlL(i, 0), bl0, vA, vA,
                                                          vH, SoutV, mask, avgV, nullptr,
                                                          nullptr, 1.f / BN, N);
            }

            spmm_csr_kernel<1><<<RD / 32, 1024, 0, stream>>>(ptrD, edgesD,
                                                             (const __half2*)vH, msg, RD,
                                                             slot(i, 1));
            gemm_mfma<0><<<BF / 64, 256, 0, stream>>>(fA, msg, slot(i, 1), g1, be1,
                                                      WhL(i, 1), WlL(i, 1), bl1, nullptr,
                                                      fA, fH,
                                                      (i < 14) ? slot(i + 2, 1) : Sfinal,
                                                      nullptr, nullptr, nullptr, nullptr,
                                                      1.f / BF, Fn);
        } else {
            for (int j = 0; j < 2; ++j) {
                const float* g = rn_gamma + (size_t)(i * 2 + j) * 256;
                const float* be = rn_beta + (size_t)(i * 2 + j) * 256;
                const float* bl = rn_b + (size_t)(i * 2 + j) * 128;
                const float* src = (j == 0) ? vA : msg;
                float* dst = (j == 0) ? msg : vA;
                const float* resid = (j == 0) ? nullptr : vA;
                __half* shadow = (j == 0) ? nullptr : vH;
                float* SoutP = (j == 0) ? slot(i, 1) : slot(i + 1, 0);
                float* avgO = (j == 0) ? (Aarena + 512 * i) : nullptr;
                const float* avgacc = Aarena + 512 * (i - 1 + j);

                gemm_mfma<1><<<BN / 64, 256, 0, stream>>>(src, nullptr, slot(i, j), g, be,
                                                          WhL(i, j), WlL(i, j), bl, resid,
                                                          dst, shadow, SoutP, mask, avgO,
                                                          avgacc, msum, 1.f / BN, N);
            }
        }
    }

    fold_final<<<1, 128, 0, stream>>>(Sfinal, g2, be2, W2, b2, W2p, 1.f / BF);
    final_out_kernel<<<BF / 16, 256, 0, stream>>>(fA, W2p, out);
}

// Round 9
// 3976.029 us; speedup vs baseline: 1.0859x; 1.0859x over previous
//
#include <hip/hip_runtime.h>
#include <hip/hip_fp16.h>
#include <math.h>

// DirModelToFace on MI355X — round 23:
//  * Base = r20 (champion 4150us: W-side fold-in-gemm LDS structure, avg-layer
//    kbEnd=4 algebraic bias fold, single-pass CSR, conv1+masksum).
//  * ONLY change: gemm_mfma 256 -> 512 threads/block. 8 waves x 16 rows x
//    128 cols (acc[8]); W tile staged once per block exactly as before.
//    Grid unchanged (375/750) -> resident waves DOUBLE at identical
//    FETCH/WRITE and identical barrier count. Isolates "TLP at fixed traffic"
//    (r22 confounded TLP with 2x W-traffic + halved per-wave ILP).

#define EPS 1e-5f

typedef float floatx4 __attribute__((ext_vector_type(4)));
typedef short shortx8 __attribute__((ext_vector_type(8)));

__device__ __forceinline__ float eluf(float x) { return x > 0.f ? x : expm1f(x); }
__device__ __forceinline__ float4 elu4(float4 v) {
    v.x = eluf(v.x); v.y = eluf(v.y); v.z = eluf(v.z); v.w = eluf(v.w); return v;
}
__device__ __forceinline__ short f2bf(float x) {  // round-to-nearest-even bf16
    unsigned u = __builtin_bit_cast(unsigned, x);
    u = u + 0x7FFFu + ((u >> 16) & 1u);
    return (short)(u >> 16);
}
__device__ __forceinline__ float bf2f(short h) {
    unsigned u = ((unsigned)(unsigned short)h) << 16;
    return __builtin_bit_cast(float, u);
}
// truncation hi/lo split: rem = x-bf2f(hi) exact in fp32; total err <= 2^-16|x|
__device__ __forceinline__ void split2(float x, short& hi, short& lo) {
    unsigned u = __builtin_bit_cast(unsigned, x);
    hi = (short)(u >> 16);
    float r = x - bf2f(hi);
    lo = (short)(__builtin_bit_cast(unsigned, r) >> 16);
}

// v = inputs @ W1 + b1; fp16 shadow; fused elu-stats (A-half of dir0 slot0).
// Blocks >= nConv do the masksum reduction (merged former masksum_kernel).
__global__ void conv1_kernel(const float* __restrict__ in, const float* __restrict__ W1,
                             const float* __restrict__ b1, float* __restrict__ v,
                             __half* __restrict__ vH, int N, float* __restrict__ Sout,
                             const float* __restrict__ mask, float* __restrict__ msum,
                             int nConv) {
    __shared__ float sh[4];
    int t = threadIdx.x;
    if (blockIdx.x >= nConv) {  // masksum for batch b
        int b = blockIdx.x - nConv;
        float s = 0.f;
        for (int n = t; n < N; n += 256) s += mask[(size_t)b * N + n];
        for (int o = 32; o > 0; o >>= 1) s += __shfl_down(s, o);
        if ((t & 63) == 0) sh[t >> 6] = s;
        __syncthreads();
        if (t == 0) msum[b] = sh[0] + sh[1] + sh[2] + sh[3];
        return;
    }
    int c = t & 127, half = t >> 7;
    int r0 = blockIdx.x * 64;
    float w0 = W1[c], w1 = W1[128 + c], w2 = W1[256 + c], bb = b1[c];
    float s1 = 0.f, s2 = 0.f;
    for (int k = 0; k < 32; ++k) {
        int r = r0 + half + 2 * k;
        float x0 = in[r * 3 + 0], x1 = in[r * 3 + 1], x2 = in[r * 3 + 2];
        float val = bb + x0 * w0 + x1 * w1 + x2 * w2;
        v[(size_t)r * 128 + c] = val;
        int b = r / N, vert = r - b * N;
        vH[(size_t)(4 * vert + (c >> 5)) * 128 + b * 32 + (c & 31)] = __float2half(val);
        float e = eluf(val);
        s1 += e; s2 += e * e;
    }
    atomicAdd(&Sout[c], s1);
    atomicAdd(&Sout[256 + c], s2);
}

// ---------------- CSR build (A and D merged via blockIdx.y) ----------------

__global__ void hist2_kernel(const int* __restrict__ rowsA, const int* __restrict__ rowsD,
                             int* __restrict__ cntA, int* __restrict__ cntD) {
    int e = blockIdx.x * 256 + threadIdx.x;
    if (blockIdx.y == 0) atomicAdd(&cntA[rowsA[e]], 1);
    else atomicAdd(&cntD[rowsD[e]], 1);
}

__global__ void partial2_kernel(const int* __restrict__ cntA, const int* __restrict__ cntD,
                                int* __restrict__ partA, int* __restrict__ partD,
                                int RA, int RD) {
    const int* counts = blockIdx.y ? cntD : cntA;
    int* partials = blockIdx.y ? partD : partA;
    int R = blockIdx.y ? RD : RA;
    int t = threadIdx.x;
    int base = blockIdx.x * 1024 + t * 4;
    int s = 0;
#pragma unroll
    for (int j = 0; j < 4; ++j) { int i = base + j; if (i < R) s += counts[i]; }
    __shared__ int sh[256];
    sh[t] = s; __syncthreads();
    for (int st = 128; st > 0; st >>= 1) {
        if (t < st) sh[t] += sh[t + st];
        __syncthreads();
    }
    if (t == 0) partials[blockIdx.x] = sh[0];
}

__global__ void scanp2_kernel(int* __restrict__ partA, int* __restrict__ partD,
                              int* __restrict__ ptrA, int* __restrict__ ptrD,
                              int PA, int PD, int RA, int RD, int total) {
    int* partials = blockIdx.y ? partD : partA;
    int* rowptr = blockIdx.y ? ptrD : ptrA;
    int P = blockIdx.y ? PD : PA;
    int R = blockIdx.y ? RD : RA;
    __shared__ int sh[256];
    int t = threadIdx.x;
    int v = (t < P) ? partials[t] : 0;
    sh[t] = v; __syncthreads();
    for (int st = 1; st < 256; st <<= 1) {
        int tmp = (t >= st) ? sh[t - st] : 0;
        __syncthreads();
        sh[t] += tmp;
        __syncthreads();
    }
    if (t < P) partials[t] = sh[t] - v;
    if (t == 0) rowptr[R] = total;
}

__global__ void apply2_kernel(int* __restrict__ cntA, int* __restrict__ cntD,
                              const int* __restrict__ partA, const int* __restrict__ partD,
                              int* __restrict__ ptrA, int* __restrict__ ptrD,
                              int RA, int RD) {
    int* counts = blockIdx.y ? cntD : cntA;
    const int* partials = blockIdx.y ? partD : partA;
    int* rowptr = blockIdx.y ? ptrD : ptrA;
    int R = blockIdx.y ? RD : RA;
    int t = threadIdx.x;
    int base = blockIdx.x * 1024 + t * 4;
    int c[4]; int s = 0;
#pragma unroll
    for (int j = 0; j < 4; ++j) { int i = base + j; c[j] = (i < R) ? counts[i] : 0; s += c[j]; }
    __shared__ int sh[256];
    sh[t] = s; __syncthreads();
    for (int st = 1; st < 256; st <<= 1) {
        int tmp = (t >= st) ? sh[t - st] : 0;
        __syncthreads();
        sh[t] += tmp;
        __syncthreads();
    }
    int off = partials[blockIdx.x] + sh[t] - s;
#pragma unroll
    for (int j = 0; j < 4; ++j) {
        int i = base + j;
        if (i < R) { rowptr[i] = off; counts[i] = off; }
        off += c[j];
    }
}

__global__ void scatter2_kernel(const int* __restrict__ rowsA, const int* __restrict__ colsA,
                                const float* __restrict__ valsA,
                                const int* __restrict__ rowsD, const int* __restrict__ colsD,
                                const float* __restrict__ valsD,
                                int* __restrict__ fillA, int* __restrict__ fillD,
                                int2* __restrict__ edgesA, int2* __restrict__ edgesD) {
    int e = blockIdx.x * 256 + threadIdx.x;
    if (blockIdx.y == 0) {
        int p = atomicAdd(&fillA[rowsA[e]], 1);
        edgesA[p] = make_int2(colsA[e], __float_as_int(valsA[e]));
    } else {
        int p = atomicAdd(&fillD[rowsD[e]], 1);
        edgesD[p] = make_int2(colsD[e], __float_as_int(valsD[e]));
    }
}

// ---- CSR spmm: 16 waves/block, 2 rows/wave, 1 dword gather/edge, fused B stats ----
template <int DIR>
__global__ __launch_bounds__(1024) void spmm_csr_kernel(
    const int* __restrict__ rowptr, const int2* __restrict__ edges,
    const __half2* __restrict__ xH, float* __restrict__ y, int R4,
    float* __restrict__ Sout) {
    int t = threadIdx.x;
    int waveId = blockIdx.x * 16 + (t >> 6);
    int lane = t & 63;
    int b = lane >> 4, cp = lane & 15;
    const __half2* xb = xH + b * 16 + cp;
    size_t rs = (size_t)R4 * 32;
    __shared__ float red[256];
    if (t < 256) red[t] = 0.f;
    __syncthreads();
#pragma unroll
    for (int rr = 0; rr < 2; ++rr) {
        int r = waveId * 2 + rr;
        int e0 = rowptr[r], e1 = rowptr[r + 1];
        float ax = 0.f, ay = 0.f;
        int e = e0;
        for (; e + 4 <= e1; e += 4) {
            int2 E0 = edges[e], E1 = edges[e + 1], E2 = edges[e + 2], E3 = edges[e + 3];
            __half2 g0 = xb[(size_t)E0.x * 64];
            __half2 g1 = xb[(size_t)E1.x * 64];
            __half2 g2 = xb[(size_t)E2.x * 64];
            __half2 g3 = xb[(size_t)E3.x * 64];
            float v0 = __int_as_float(E0.y), v1 = __int_as_float(E1.y);
            float v2 = __int_as_float(E2.y), v3 = __int_as_float(E3.y);
            float2 f0 = __half22float2(g0), f1 = __half22float2(g1);
            float2 f2 = __half22float2(g2), f3 = __half22float2(g3);
            ax += v0 * f0.x; ay += v0 * f0.y;
            ax += v1 * f1.x; ay += v1 * f1.y;
            ax += v2 * f2.x; ay += v2 * f2.y;
            ax += v3 * f3.x; ay += v3 * f3.y;
        }
        for (; e < e1; ++e) {
            int2 E = edges[e];
            __half2 g = xb[(size_t)E.x * 64];
            float v = __int_as_float(E.y);
            float2 f = __half22float2(g);
            ax += v * f.x; ay += v * f.y;
        }
        *(float2*)&y[(size_t)b * rs + (size_t)r * 32 + cp * 2] = make_float2(ax, ay);
        float ea = eluf(ax), eb = eluf(ay);
        float s1a = ea, s2a = ea * ea, s1b = eb, s2b = eb * eb;
        s1a += __shfl_xor(s1a, 16); s1a += __shfl_xor(s1a, 32);
        s2a += __shfl_xor(s2a, 16); s2a += __shfl_xor(s2a, 32);
        s1b += __shfl_xor(s1b, 16); s1b += __shfl_xor(s1b, 32);
        s2b += __shfl_xor(s2b, 16); s2b += __shfl_xor(s2b, 32);
        if (lane < 16) {
            int ch = (r & 3) * 32 + cp * 2;
            atomicAdd(&red[ch], s1a);
            atomicAdd(&red[ch + 1], s1b);
            atomicAdd(&red[128 + ch], s2a);
            atomicAdd(&red[128 + ch + 1], s2b);
        }
    }
    __syncthreads();
    if (t < 128) atomicAdd(&Sout[128 + t], red[t]);
    else if (t < 256) atomicAdd(&Sout[384 + (t - 128)], red[t]);
}

// MFMA GEMM, 512 threads (8 waves x 16 rows), 128-row tile, W-side fold in LDS.
// MODEB: 0 = per-row fp32 B (msg, elu), 1 = avg layer (B-half folded into a
// per-batch BIAS, kbEnd=4), 2 = B zero (kbEnd=4, sMS bias pass only).
template <int MODEB>
__global__ __launch_bounds__(512) void gemm_mfma(
    const float* __restrict__ A, const float* __restrict__ Bs,
    const float* __restrict__ S, const float* __restrict__ gvec,
    const float* __restrict__ bevec, const float* __restrict__ Wfull,
    const float* __restrict__ bvec, const float* __restrict__ resid,
    float* __restrict__ out, __half* __restrict__ shadow,
    float* __restrict__ Sout, const float* __restrict__ mask,
    float* __restrict__ avgout, const float* __restrict__ avgacc,
    const float* __restrict__ msum, float invR, int rowsPerBatch) {
    __shared__ short Bsh[128 * 40];
    __shared__ short Bsl[128 * 40];
    __shared__ float sS[256];
    __shared__ float sMS[256];
    __shared__ float avgLDS[512];
    __shared__ float bparr[512];
    __shared__ float bparrX[2][512];
    __shared__ float bpF2[2][128];
    const int t = threadIdx.x;
    const int lane = t & 63;
    const int wave = t >> 6;                 // 8 waves
    const int rowBase = blockIdx.x * 128 + wave * 16;
    const int m = lane & 15;
    const int kq = lane >> 4;
    constexpr int kbEnd = (MODEB == 0) ? 8 : 4;
    const int colW = t & 127;
    const int qs0 = t >> 7;                  // 0..3: each thread stages ONE shortx8
    const int bBlk = (blockIdx.x * 128) / rowsPerBatch;  // block spans <=2 batches
    const int arow = rowBase + m;

    // ---- per-block BN fold prologue (exact former fold_kernel arithmetic) ----
    if (t < 256) {
        int k = t;
        float mean, var;
        if (MODEB == 1 && k >= 128) {
            int c = k - 128;
            float a0 = avgacc[c] / msum[0];
            float a1 = avgacc[128 + c] / msum[1];
            float a2 = avgacc[256 + c] / msum[2];
            float a3 = avgacc[384 + c] / msum[3];
            avgLDS[c] = a0; avgLDS[128 + c] = a1;
            avgLDS[256 + c] = a2; avgLDS[384 + c] = a3;
            mean = 0.25f * (a0 + a1 + a2 + a3);
            var = 0.25f * (a0 * a0 + a1 * a1 + a2 * a2 + a3 * a3) - mean * mean;
        } else {
            mean = S[k] * invR;
            var = S[256 + k] * invR - mean * mean;
        }
        float s = gvec[k] / sqrtf(var + EPS);
        sS[k] = s;
        sMS[k] = bevec[k] - mean * s;
    }
    // first __syncthreads() of the kb loop guards sS/sMS/avgLDS.

    floatx4 acc[8];
#pragma unroll
    for (int j = 0; j < 8; ++j) acc[j] = {0.f, 0.f, 0.f, 0.f};

    float bpp = 0.f;  // per-thread bias-fold partial (col = t&127, qs = qs0)
    for (int kb = 0; kb < kbEnd; ++kb) {
        const int k0 = kb * 32 + kq * 8;
        __syncthreads();
        // ---- stage W tile: each thread folds ONE shortx8 (col=colW, qs=qs0) ----
        {
            shortx8 hv, lv;
#pragma unroll
            for (int j = 0; j < 8; ++j) {
                int k = kb * 32 + qs0 * 8 + j;
                float w = Wfull[(size_t)k * 128 + colW];
                float wp = sS[k] * w;
                short h = f2bf(wp);
                hv[j] = h;
                lv[j] = f2bf(wp - bf2f(h));
                bpp += sMS[k] * w;
            }
            *(shortx8*)&Bsh[colW * 40 + qs0 * 8] = hv;
            *(shortx8*)&Bsl[colW * 40 + qs0 * 8] = lv;
        }
        // ---- A frag for this wave's 16 rows ----
        shortx8 ah, al;
        {
            float4 p, q;
            if (kb < 4) {
                p = elu4(*(const float4*)&A[(size_t)arow * 128 + k0]);
                q = elu4(*(const float4*)&A[(size_t)arow * 128 + k0 + 4]);
            } else {  // only MODEB==0 reaches here
                int kk = k0 - 128;
                p = elu4(*(const float4*)&Bs[(size_t)arow * 128 + kk]);
                q = elu4(*(const float4*)&Bs[(size_t)arow * 128 + kk + 4]);
            }
            float x[8] = {p.x, p.y, p.z, p.w, q.x, q.y, q.z, q.w};
#pragma unroll
            for (int j = 0; j < 8; ++j) { short h, l; split2(x[j], h, l); ah[j] = h; al[j] = l; }
        }
        __syncthreads();
#pragma unroll
        for (int ct = 0; ct < 8; ++ct) {
            const int co = (ct * 16 + m) * 40 + kq * 8;
            shortx8 bh = *(const shortx8*)&Bsh[co];
            shortx8 bl = *(const shortx8*)&Bsl[co];
            acc[ct] = __builtin_amdgcn_mfma_f32_16x16x32_bf16(ah, bh, acc[ct], 0, 0, 0);
            acc[ct] = __builtin_amdgcn_mfma_f32_16x16x32_bf16(ah, bl, acc[ct], 0, 0, 0);
            acc[ct] = __builtin_amdgcn_mfma_f32_16x16x32_bf16(al, bh, acc[ct], 0, 0, 0);
        }
    }

    // ---- bias for skipped k>=128 ----
    float bps0 = 0.f, bps1 = 0.f;   // per-spanned-batch extras
    if (MODEB == 2) {
        // B input is identically 0: only the sMS[k]*W term for k>=128.
        for (int j = 0; j < 32; ++j) {
            int k = 128 + qs0 * 32 + j;
            bps0 += sMS[k] * Wfull[(size_t)k * 128 + colW];
        }
        bps1 = bps0;
    } else if (MODEB == 1) {
        // B-half is a per-batch broadcast: fold into per-batch bias
        //   sum_k (sMS[k] + avg[b][k-128]*sS[k]) * W[k][col], fp32-exact.
        const int b0 = bBlk, b1 = (bBlk + 1 < 4) ? bBlk + 1 : 3;
        for (int j = 0; j < 32; ++j) {
            int k = 128 + qs0 * 32 + j;
            float w = Wfull[(size_t)k * 128 + colW];
            float sw = sS[k] * w;
            float base = sMS[k] * w;
            bps0 += base + avgLDS[b0 * 128 + (k - 128)] * sw;
            bps1 += base + avgLDS[b1 * 128 + (k - 128)] * sw;
        }
    }
    // ---- finish bias fold (4 threads share col = t&127) ----
    bparr[t] = bpp;
    bparrX[0][t] = bps0;
    bparrX[1][t] = bps1;
    __syncthreads();
    if (t < 128) {
        float common = bvec[t] + bparr[t] + bparr[t + 128] + bparr[t + 256] + bparr[t + 384];
        bpF2[0][t] = common + bparrX[0][t] + bparrX[0][t + 128] + bparrX[0][t + 256] + bparrX[0][t + 384];
        bpF2[1][t] = common + bparrX[1][t] + bparrX[1][t + 128] + bparrX[1][t + 256] + bparrX[1][t + 384];
    }
    __syncthreads();

    // epilogue: C/D layout col=lane&15, row=(lane>>4)*4+reg  [verified m89/m91]
    float mk4[4]; int ib4[4];
#pragma unroll
    for (int r = 0; r < 4; ++r) {
        int row = rowBase + kq * 4 + r;
        ib4[r] = (row >= (bBlk + 1) * rowsPerBatch) ? 1 : 0;
        if (avgout) mk4[r] = mask[row];
    }
    float cs1[8], cs2[8], av0[8], av1[8];
#pragma unroll
    for (int ct = 0; ct < 8; ++ct) { cs1[ct] = 0.f; cs2[ct] = 0.f; av0[ct] = 0.f; av1[ct] = 0.f; }
#pragma unroll
    for (int ct = 0; ct < 8; ++ct) {
        int col = ct * 16 + m;
        float bb0 = bpF2[0][col], bb1 = bpF2[1][col];
#pragma unroll
        for (int r = 0; r < 4; ++r) {
            int row = rowBase + kq * 4 + r;
            size_t o = (size_t)row * 128 + col;
            float v = acc[ct][r] + (ib4[r] ? bb1 : bb0);
            if (resid) v += resid[o];
            out[o] = v;
            if (shadow) {
                int b = row / rowsPerBatch, vert = row - b * rowsPerBatch;
                shadow[(size_t)(4 * vert + (col >> 5)) * 128 + b * 32 + (col & 31)] =
                    __float2half(v);
            }
            float e = eluf(v);
            cs1[ct] += e; cs2[ct] += e * e;
            if (avgout) {
                float me = mk4[r] * e;
                if (ib4[r]) av1[ct] += me; else av0[ct] += me;
            }
        }
    }
    if (Sout) {  // fused stats (+ optional avg numerators) for the consuming layer
        __syncthreads();
        float* red = (float*)Bsh;
        float* redv = (float*)Bsl;
        if (t < 256) {
            red[t] = 0.f;
            if (avgout) redv[t] = 0.f;
        }
        __syncthreads();
#pragma unroll
        for (int ct = 0; ct < 8; ++ct) {
            cs1[ct] += __shfl_xor(cs1[ct], 16); cs1[ct] += __shfl_xor(cs1[ct], 32);
            cs2[ct] += __shfl_xor(cs2[ct], 16); cs2[ct] += __shfl_xor(cs2[ct], 32);
            if (avgout) {
                av0[ct] += __shfl_xor(av0[ct], 16); av0[ct] += __shfl_xor(av0[ct], 32);
                av1[ct] += __shfl_xor(av1[ct], 16); av1[ct] += __shfl_xor(av1[ct], 32);
            }
        }
        if (kq == 0) {
#pragma unroll
            for (int ct = 0; ct < 8; ++ct) {
                atomicAdd(&red[ct * 16 + m], cs1[ct]);
                atomicAdd(&red[128 + ct * 16 + m], cs2[ct]);
                if (avgout) {
                    atomicAdd(&redv[ct * 16 + m], av0[ct]);
                    atomicAdd(&redv[128 + ct * 16 + m], av1[ct]);
                }
            }
        }
        __syncthreads();
        if (t < 128) atomicAdd(&Sout[t], red[t]);
        else if (t < 256) atomicAdd(&Sout[256 + (t - 128)], red[t]);
        if (avgout && t < 256) {
            int plane = t >> 7, col = t & 127;
            int b = bBlk + plane;
            if (b < 4) atomicAdd(&avgout[b * 128 + col], redv[t]);
        }
    }
}

__global__ void fold_final(const float* __restrict__ S, const float* __restrict__ g2,
                           const float* __restrict__ be2, const float* __restrict__ W2,
                           const float* __restrict__ b2, float* __restrict__ W2p, float invR) {
    __shared__ float red[128];
    int c = threadIdx.x;
    float mean = S[c] * invR;
    float var = S[256 + c] * invR - mean * mean;
    float s = g2[c] / sqrtf(var + EPS);
    float w = W2[c];
    W2p[c] = s * w;
    red[c] = (be2[c] - mean * s) * w;
    __syncthreads();
    for (int st = 64; st > 0; st >>= 1) {
        if (c < st) red[c] += red[c + st];
        __syncthreads();
    }
    if (c == 0) W2p[128] = b2[0] + red[0];
}

__global__ void final_out_kernel(const float* __restrict__ f, const float* __restrict__ W2p,
                                 float* __restrict__ out) {
    int t = threadIdx.x;
    int w = t >> 6, lane = t & 63;
    float wa = W2p[lane], wb = W2p[64 + lane], bb = W2p[128];
    int base = blockIdx.x * 16 + w * 4;
#pragma unroll
    for (int rr = 0; rr < 4; ++rr) {
        int row = base + rr;
        float a = eluf(f[(size_t)row * 128 + lane]) * wa +
                  eluf(f[(size_t)row * 128 + 64 + lane]) * wb;
        for (int off = 32; off > 0; off >>= 1) a += __shfl_down(a, off);
        if (lane == 0) out[row] = a + bb;
    }
}

extern "C" void kernel_launch(void* const* d_in, const int* in_sizes, int n_in,
                              void* d_out, int out_size, void* d_ws, size_t ws_size,
                              hipStream_t stream) {
    const float* inputs = (const float*)d_in[0];
    const float* mask = (const float*)d_in[1];
    const int* Di_rows = (const int*)d_in[2];
    const int* Di_cols = (const int*)d_in[3];
    const float* Di_vals = (const float*)d_in[4];
    const int* DiA_rows = (const int*)d_in[5];
    const int* DiA_cols = (const int*)d_in[6];
    const float* DiA_vals = (const float*)d_in[7];
    const float* W1 = (const float*)d_in[8];
    const float* b1 = (const float*)d_in[9];
    const float* rn_gamma = (const float*)d_in[10];
    const float* rn_beta = (const float*)d_in[11];
    const float* rn_W = (const float*)d_in[12];
    const float* rn_b = (const float*)d_in[13];
    const float* g2 = (const float*)d_in[14];
    const float* be2 = (const float*)d_in[15];
    const float* W2 = (const float*)d_in[16];
    const float* b2 = (const float*)d_in[17];
    float* out = (float*)d_out;

    const int B = 4;
    const int BN = in_sizes[1];      // 48000
    const int N = BN / B;            // 12000
    const int BF = out_size;         // 96000
    const int Fn = BF / B;           // 24000
    const int nnz = in_sizes[2];     // 1,152,000
    const int RA = 4 * N;            // 48000
    const int RD = 4 * Fn;           // 96000

    float* ws = (float*)d_ws;
    size_t off = 0;
    float* vA = ws + off;  off += (size_t)BN * 128;
    float* fA = ws + off;  off += (size_t)BF * 128;
    float* msg = ws + off; off += (size_t)BF * 128;   // fp32 spmm out
    __half* vH = (__half*)(ws + off); off += (size_t)RA * 128 / 2;  // [r4][b][32] fp16
    __half* fH = (__half*)(ws + off); off += (size_t)RD * 128 / 2;
    int* ptrA    = (int*)(ws + off);  off += (size_t)RA + 4;
    int2* edgesA = (int2*)(ws + off); off += (size_t)nnz * 2;
    int* ptrD    = (int*)(ws + off);  off += (size_t)RD + 4;
    int2* edgesD = (int2*)(ws + off); off += (size_t)nnz * 2;
    int* cntA    = (int*)(ws + off);  off += (size_t)RA;
    int* cntD    = (int*)(ws + off);  off += (size_t)RD;
    int* partA   = (int*)(ws + off);  off += 256;
    int* partD   = (int*)(ws + off);  off += 256;
    float* Sarena = ws + off; off += 33 * 512;   // pre-zeroed stats slots (2i+j map)
    float* Aarena = ws + off; off += 16 * 512;   // pre-zeroed avg-numerator slots
    float* msum = ws + off;   off += 4;
    float* W2p = ws + off; off += 132;

    const int eBlocks = nnz / 256;
    const int PA = (RA + 1023) / 1024;
    const int PD = (RD + 1023) / 1024;

    hipMemsetAsync(Sarena, 0, (33 * 512 + 16 * 512) * 4, stream);
    hipMemsetAsync(fA, 0, (size_t)BF * 128 * 4, stream);
    hipMemsetAsync(cntA, 0, (size_t)(RA + RD) * 4, stream);  // cntA+cntD contiguous

    // ---- build CSR for DiA and Di in one merged chain ----
    hist2_kernel<<<dim3(eBlocks, 2), 256, 0, stream>>>(DiA_rows, Di_rows, cntA, cntD);
    partial2_kernel<<<dim3(PD, 2), 256, 0, stream>>>(cntA, cntD, partA, partD, RA, RD);
    scanp2_kernel<<<dim3(1, 2), 256, 0, stream>>>(partA, partD, ptrA, ptrD, PA, PD,
                                                  RA, RD, nnz);
    apply2_kernel<<<dim3(PD, 2), 256, 0, stream>>>(cntA, cntD, partA, partD, ptrA, ptrD,
                                                   RA, RD);
    scatter2_kernel<<<dim3(eBlocks, 2), 256, 0, stream>>>(DiA_rows, DiA_cols, DiA_vals,
                                                          Di_rows, Di_cols, Di_vals,
                                                          cntA, cntD, edgesA, edgesD);

    // S slot map: conv layer (i,j) -> Sarena + 512*(2i+j); final conv -> slot 32.
    auto slot = [&](int i, int j) { return Sarena + 512 * (2 * i + j); };
    float* Sfinal = Sarena + 512 * 32;

    // conv1 + masksum merged (last B blocks do masksum)
    conv1_kernel<<<BN / 64 + B, 256, 0, stream>>>(inputs, W1, b1, vA, vH, N, slot(0, 0),
                                                  mask, msum, BN / 64);

    for (int i = 0; i < 15; ++i) {   // layer 15 (avg) is dead: output depends only on f
        if ((i & 1) == 0) {
            const float* g0 = rn_gamma + (size_t)(i * 2 + 0) * 256;
            const float* be0 = rn_beta + (size_t)(i * 2 + 0) * 256;
            const float* Wl0 = rn_W + (size_t)(i * 2 + 0) * 256 * 128;
            const float* bl0 = rn_b + (size_t)(i * 2 + 0) * 128;
            const float* g1 = rn_gamma + (size_t)(i * 2 + 1) * 256;
            const float* be1 = rn_beta + (size_t)(i * 2 + 1) * 256;
            const float* Wl1 = rn_W + (size_t)(i * 2 + 1) * 256 * 128;
            const float* bl1 = rn_b + (size_t)(i * 2 + 1) * 128;
            float* SoutV = (i < 14) ? slot(i + 1, 0) : nullptr;
            float* avgV = (i < 14) ? (Aarena + 512 * i) : nullptr;

            if (i == 0) {
                // f == 0 -> msg_v == 0 exactly: skip spmm; slot(0,0) B-half stays 0.
                gemm_mfma<2><<<BN / 128, 512, 0, stream>>>(vA, nullptr, slot(0, 0), g0, be0,
                                                           Wl0, bl0, vA, vA, vH, SoutV, mask,
                                                           avgV, nullptr, nullptr, 1.f / BN,
                                                           N);
            } else {
                spmm_csr_kernel<0><<<RA / 32, 1024, 0, stream>>>(ptrA, edgesA,
                                                                 (const __half2*)fH, msg,
                                                                 RA, slot(i, 0));
                gemm_mfma<0><<<BN / 128, 512, 0, stream>>>(vA, msg, slot(i, 0), g0, be0,
                                                           Wl0, bl0, vA, vA, vH, SoutV, mask,
                                                           avgV, nullptr, nullptr, 1.f / BN,
                                                           N);
            }

            spmm_csr_kernel<1><<<RD / 32, 1024, 0, stream>>>(ptrD, edgesD,
                                                             (const __half2*)vH, msg, RD,
                                                             slot(i, 1));
            gemm_mfma<0><<<BF / 128, 512, 0, stream>>>(fA, msg, slot(i, 1), g1, be1, Wl1,
                                                       bl1, nullptr, fA, fH,
                                                       (i < 14) ? slot(i + 2, 1) : Sfinal,
                                                       nullptr, nullptr, nullptr, nullptr,
                                                       1.f / BF, Fn);
        } else {
            for (int j = 0; j < 2; ++j) {
                const float* g = rn_gamma + (size_t)(i * 2 + j) * 256;
                const float* be = rn_beta + (size_t)(i * 2 + j) * 256;
                const float* Wlw = rn_W + (size_t)(i * 2 + j) * 256 * 128;
                const float* bl = rn_b + (size_t)(i * 2 + j) * 128;
                const float* src = (j == 0) ? vA : msg;
                float* dst = (j == 0) ? msg : vA;
                const float* resid = (j == 0) ? nullptr : vA;
                __half* shadow = (j == 0) ? nullptr : vH;
                float* SoutP = (j == 0) ? slot(i, 1) : slot(i + 1, 0);
                float* avgO = (j == 0) ? (Aarena + 512 * i) : nullptr;
                const float* avgacc = Aarena + 512 * (i - 1 + j);

                gemm_mfma<1><<<BN / 128, 512, 0, stream>>>(src, nullptr, slot(i, j), g, be,
                                                           Wlw, bl, resid, dst, shadow,
                                                           SoutP, mask, avgO, avgacc, msum,
                                                           1.f / BN, N);
            }
        }
    }

    fold_final<<<1, 128, 0, stream>>>(Sfinal, g2, be2, W2, b2, W2p, 1.f / BF);
    final_out_kernel<<<BF / 16, 256, 0, stream>>>(fA, W2p, out);
}

// Round 10
// 3918.372 us; speedup vs baseline: 1.1019x; 1.0147x over previous
//
#include <hip/hip_runtime.h>
#include <hip/hip_fp16.h>
#include <math.h>

// DirModelToFace on MI355X — round 24:
//  * Base = r23 (champion 3976us: 512-thread gemm = TLP-at-fixed-traffic WIN).
//  * spmm rework, same principle transferred: lane = (e2,b,cq) = 2 edge-slots x
//    4 batches x 8 channel-quads. Each lane gathers 8B (uint2 = 4 fp16): 32
//    lanes per edge, 2 edges concurrent per wave, unroll x4 -> 8 edges in
//    flight with HALF the load instructions (same bytes). Cross-half combine =
//    4 shfl_xor(32); stats reduce over batch = xor 8/16. Within-row sum order
//    changes (already nondeterministic via atomic scatter; tolerance proven).
//  * Everything else r23-exact.

#define EPS 1e-5f

typedef float floatx4 __attribute__((ext_vector_type(4)));
typedef short shortx8 __attribute__((ext_vector_type(8)));

__device__ __forceinline__ float eluf(float x) { return x > 0.f ? x : expm1f(x); }
__device__ __forceinline__ float4 elu4(float4 v) {
    v.x = eluf(v.x); v.y = eluf(v.y); v.z = eluf(v.z); v.w = eluf(v.w); return v;
}
__device__ __forceinline__ short f2bf(float x) {  // round-to-nearest-even bf16
    unsigned u = __builtin_bit_cast(unsigned, x);
    u = u + 0x7FFFu + ((u >> 16) & 1u);
    return (short)(u >> 16);
}
__device__ __forceinline__ float bf2f(short h) {
    unsigned u = ((unsigned)(unsigned short)h) << 16;
    return __builtin_bit_cast(float, u);
}
// truncation hi/lo split: rem = x-bf2f(hi) exact in fp32; total err <= 2^-16|x|
__device__ __forceinline__ void split2(float x, short& hi, short& lo) {
    unsigned u = __builtin_bit_cast(unsigned, x);
    hi = (short)(u >> 16);
    float r = x - bf2f(hi);
    lo = (short)(__builtin_bit_cast(unsigned, r) >> 16);
}

// v = inputs @ W1 + b1; fp16 shadow; fused elu-stats (A-half of dir0 slot0).
// Blocks >= nConv do the masksum reduction (merged former masksum_kernel).
__global__ void conv1_kernel(const float* __restrict__ in, const float* __restrict__ W1,
                             const float* __restrict__ b1, float* __restrict__ v,
                             __half* __restrict__ vH, int N, float* __restrict__ Sout,
                             const float* __restrict__ mask, float* __restrict__ msum,
                             int nConv) {
    __shared__ float sh[4];
    int t = threadIdx.x;
    if (blockIdx.x >= nConv) {  // masksum for batch b
        int b = blockIdx.x - nConv;
        float s = 0.f;
        for (int n = t; n < N; n += 256) s += mask[(size_t)b * N + n];
        for (int o = 32; o > 0; o >>= 1) s += __shfl_down(s, o);
        if ((t & 63) == 0) sh[t >> 6] = s;
        __syncthreads();
        if (t == 0) msum[b] = sh[0] + sh[1] + sh[2] + sh[3];
        return;
    }
    int c = t & 127, half = t >> 7;
    int r0 = blockIdx.x * 64;
    float w0 = W1[c], w1 = W1[128 + c], w2 = W1[256 + c], bb = b1[c];
    float s1 = 0.f, s2 = 0.f;
    for (int k = 0; k < 32; ++k) {
        int r = r0 + half + 2 * k;
        float x0 = in[r * 3 + 0], x1 = in[r * 3 + 1], x2 = in[r * 3 + 2];
        float val = bb + x0 * w0 + x1 * w1 + x2 * w2;
        v[(size_t)r * 128 + c] = val;
        int b = r / N, vert = r - b * N;
        vH[(size_t)(4 * vert + (c >> 5)) * 128 + b * 32 + (c & 31)] = __float2half(val);
        float e = eluf(val);
        s1 += e; s2 += e * e;
    }
    atomicAdd(&Sout[c], s1);
    atomicAdd(&Sout[256 + c], s2);
}

// ---------------- CSR build (A and D merged via blockIdx.y) ----------------

__global__ void hist2_kernel(const int* __restrict__ rowsA, const int* __restrict__ rowsD,
                             int* __restrict__ cntA, int* __restrict__ cntD) {
    int e = blockIdx.x * 256 + threadIdx.x;
    if (blockIdx.y == 0) atomicAdd(&cntA[rowsA[e]], 1);
    else atomicAdd(&cntD[rowsD[e]], 1);
}

__global__ void partial2_kernel(const int* __restrict__ cntA, const int* __restrict__ cntD,
                                int* __restrict__ partA, int* __restrict__ partD,
                                int RA, int RD) {
    const int* counts = blockIdx.y ? cntD : cntA;
    int* partials = blockIdx.y ? partD : partA;
    int R = blockIdx.y ? RD : RA;
    int t = threadIdx.x;
    int base = blockIdx.x * 1024 + t * 4;
    int s = 0;
#pragma unroll
    for (int j = 0; j < 4; ++j) { int i = base + j; if (i < R) s += counts[i]; }
    __shared__ int sh[256];
    sh[t] = s; __syncthreads();
    for (int st = 128; st > 0; st >>= 1) {
        if (t < st) sh[t] += sh[t + st];
        __syncthreads();
    }
    if (t == 0) partials[blockIdx.x] = sh[0];
}

__global__ void scanp2_kernel(int* __restrict__ partA, int* __restrict__ partD,
                              int* __restrict__ ptrA, int* __restrict__ ptrD,
                              int PA, int PD, int RA, int RD, int total) {
    int* partials = blockIdx.y ? partD : partA;
    int* rowptr = blockIdx.y ? ptrD : ptrA;
    int P = blockIdx.y ? PD : PA;
    int R = blockIdx.y ? RD : RA;
    __shared__ int sh[256];
    int t = threadIdx.x;
    int v = (t < P) ? partials[t] : 0;
    sh[t] = v; __syncthreads();
    for (int st = 1; st < 256; st <<= 1) {
        int tmp = (t >= st) ? sh[t - st] : 0;
        __syncthreads();
        sh[t] += tmp;
        __syncthreads();
    }
    if (t < P) partials[t] = sh[t] - v;
    if (t == 0) rowptr[R] = total;
}

__global__ void apply2_kernel(int* __restrict__ cntA, int* __restrict__ cntD,
                              const int* __restrict__ partA, const int* __restrict__ partD,
                              int* __restrict__ ptrA, int* __restrict__ ptrD,
                              int RA, int RD) {
    int* counts = blockIdx.y ? cntD : cntA;
    const int* partials = blockIdx.y ? partD : partA;
    int* rowptr = blockIdx.y ? ptrD : ptrA;
    int R = blockIdx.y ? RD : RA;
    int t = threadIdx.x;
    int base = blockIdx.x * 1024 + t * 4;
    int c[4]; int s = 0;
#pragma unroll
    for (int j = 0; j < 4; ++j) { int i = base + j; c[j] = (i < R) ? counts[i] : 0; s += c[j]; }
    __shared__ int sh[256];
    sh[t] = s; __syncthreads();
    for (int st = 1; st < 256; st <<= 1) {
        int tmp = (t >= st) ? sh[t - st] : 0;
        __syncthreads();
        sh[t] += tmp;
        __syncthreads();
    }
    int off = partials[blockIdx.x] + sh[t] - s;
#pragma unroll
    for (int j = 0; j < 4; ++j) {
        int i = base + j;
        if (i < R) { rowptr[i] = off; counts[i] = off; }
        off += c[j];
    }
}

__global__ void scatter2_kernel(const int* __restrict__ rowsA, const int* __restrict__ colsA,
                                const float* __restrict__ valsA,
                                const int* __restrict__ rowsD, const int* __restrict__ colsD,
                                const float* __restrict__ valsD,
                                int* __restrict__ fillA, int* __restrict__ fillD,
                                int2* __restrict__ edgesA, int2* __restrict__ edgesD) {
    int e = blockIdx.x * 256 + threadIdx.x;
    if (blockIdx.y == 0) {
        int p = atomicAdd(&fillA[rowsA[e]], 1);
        edgesA[p] = make_int2(colsA[e], __float_as_int(valsA[e]));
    } else {
        int p = atomicAdd(&fillD[rowsD[e]], 1);
        edgesD[p] = make_int2(colsD[e], __float_as_int(valsD[e]));
    }
}

// ---- CSR spmm: 16 waves/block, 2 rows/wave, wide 8B gathers ----
// lane = (e2,b,cq): 2 edge slots x 4 batches x 8 channel-quads. 32 lanes/edge,
// 2 edges concurrent/wave, unroll x4 => 8 edges in flight, half the loads.
template <int DIR>
__global__ __launch_bounds__(1024) void spmm_csr_kernel(
    const int* __restrict__ rowptr, const int2* __restrict__ edges,
    const __half2* __restrict__ xH, float* __restrict__ y, int R4,
    float* __restrict__ Sout) {
    int t = threadIdx.x;
    int waveId = blockIdx.x * 16 + (t >> 6);
    int lane = t & 63;
    int e2 = lane >> 5;            // edge slot (0/1)
    int b = (lane >> 3) & 3;       // batch
    int cq = lane & 7;             // channel quad (4 fp16)
    const uint2* xb = (const uint2*)xH + b * 8 + cq;   // 8B granule
    size_t rs = (size_t)R4 * 32;
    __shared__ float red[256];
    if (t < 256) red[t] = 0.f;
    __syncthreads();
#pragma unroll
    for (int rr = 0; rr < 2; ++rr) {
        int r = waveId * 2 + rr;
        int e0 = rowptr[r], e1 = rowptr[r + 1];
        float4 a = make_float4(0.f, 0.f, 0.f, 0.f);
        int e = e0 + e2;
        for (; e + 6 < e1; e += 8) {   // this half-wave: edges e, e+2, e+4, e+6
            int2 E0 = edges[e], E1 = edges[e + 2], E2 = edges[e + 4], E3 = edges[e + 6];
            uint2 g0 = xb[(size_t)E0.x * 32];
            uint2 g1 = xb[(size_t)E1.x * 32];
            uint2 g2 = xb[(size_t)E2.x * 32];
            uint2 g3 = xb[(size_t)E3.x * 32];
            float v0 = __int_as_float(E0.y), v1 = __int_as_float(E1.y);
            float v2 = __int_as_float(E2.y), v3 = __int_as_float(E3.y);
            float2 fa, fb;
            fa = __half22float2(__builtin_bit_cast(__half2, g0.x));
            fb = __half22float2(__builtin_bit_cast(__half2, g0.y));
            a.x += v0 * fa.x; a.y += v0 * fa.y; a.z += v0 * fb.x; a.w += v0 * fb.y;
            fa = __half22float2(__builtin_bit_cast(__half2, g1.x));
            fb = __half22float2(__builtin_bit_cast(__half2, g1.y));
            a.x += v1 * fa.x; a.y += v1 * fa.y; a.z += v1 * fb.x; a.w += v1 * fb.y;
            fa = __half22float2(__builtin_bit_cast(__half2, g2.x));
            fb = __half22float2(__builtin_bit_cast(__half2, g2.y));
            a.x += v2 * fa.x; a.y += v2 * fa.y; a.z += v2 * fb.x; a.w += v2 * fb.y;
            fa = __half22float2(__builtin_bit_cast(__half2, g3.x));
            fb = __half22float2(__builtin_bit_cast(__half2, g3.y));
            a.x += v3 * fa.x; a.y += v3 * fa.y; a.z += v3 * fb.x; a.w += v3 * fb.y;
        }
        for (; e < e1; e += 2) {
            int2 E = edges[e];
            uint2 g = xb[(size_t)E.x * 32];
            float v = __int_as_float(E.y);
            float2 fa = __half22float2(__builtin_bit_cast(__half2, g.x));
            float2 fb = __half22float2(__builtin_bit_cast(__half2, g.y));
            a.x += v * fa.x; a.y += v * fa.y; a.z += v * fb.x; a.w += v * fb.y;
        }
        // combine the two half-wave partial sums
        a.x += __shfl_xor(a.x, 32);
        a.y += __shfl_xor(a.y, 32);
        a.z += __shfl_xor(a.z, 32);
        a.w += __shfl_xor(a.w, 32);
        if (e2 == 0)
            *(float4*)&y[(size_t)b * rs + (size_t)r * 32 + cq * 4] = a;
        // fused stats for the consuming layer's B-half
        float4 ev = make_float4(eluf(a.x), eluf(a.y), eluf(a.z), eluf(a.w));
        float4 s1 = ev;
        float4 s2 = make_float4(ev.x * ev.x, ev.y * ev.y, ev.z * ev.z, ev.w * ev.w);
        s1.x += __shfl_xor(s1.x, 8); s1.x += __shfl_xor(s1.x, 16);
        s1.y += __shfl_xor(s1.y, 8); s1.y += __shfl_xor(s1.y, 16);
        s1.z += __shfl_xor(s1.z, 8); s1.z += __shfl_xor(s1.z, 16);
        s1.w += __shfl_xor(s1.w, 8); s1.w += __shfl_xor(s1.w, 16);
        s2.x += __shfl_xor(s2.x, 8); s2.x += __shfl_xor(s2.x, 16);
        s2.y += __shfl_xor(s2.y, 8); s2.y += __shfl_xor(s2.y, 16);
        s2.z += __shfl_xor(s2.z, 8); s2.z += __shfl_xor(s2.z, 16);
        s2.w += __shfl_xor(s2.w, 8); s2.w += __shfl_xor(s2.w, 16);
        if (lane < 8) {   // e2==0, b==0
            int ch = (r & 3) * 32 + cq * 4;
            atomicAdd(&red[ch + 0], s1.x); atomicAdd(&red[ch + 1], s1.y);
            atomicAdd(&red[ch + 2], s1.z); atomicAdd(&red[ch + 3], s1.w);
            atomicAdd(&red[128 + ch + 0], s2.x); atomicAdd(&red[128 + ch + 1], s2.y);
            atomicAdd(&red[128 + ch + 2], s2.z); atomicAdd(&red[128 + ch + 3], s2.w);
        }
    }
    __syncthreads();
    if (t < 128) atomicAdd(&Sout[128 + t], red[t]);
    else if (t < 256) atomicAdd(&Sout[384 + (t - 128)], red[t]);
}

// MFMA GEMM, 512 threads (8 waves x 16 rows), 128-row tile, W-side fold in LDS.
// MODEB: 0 = per-row fp32 B (msg, elu), 1 = avg layer (B-half folded into a
// per-batch BIAS, kbEnd=4), 2 = B zero (kbEnd=4, sMS bias pass only).
template <int MODEB>
__global__ __launch_bounds__(512) void gemm_mfma(
    const float* __restrict__ A, const float* __restrict__ Bs,
    const float* __restrict__ S, const float* __restrict__ gvec,
    const float* __restrict__ bevec, const float* __restrict__ Wfull,
    const float* __restrict__ bvec, const float* __restrict__ resid,
    float* __restrict__ out, __half* __restrict__ shadow,
    float* __restrict__ Sout, const float* __restrict__ mask,
    float* __restrict__ avgout, const float* __restrict__ avgacc,
    const float* __restrict__ msum, float invR, int rowsPerBatch) {
    __shared__ short Bsh[128 * 40];
    __shared__ short Bsl[128 * 40];
    __shared__ float sS[256];
    __shared__ float sMS[256];
    __shared__ float avgLDS[512];
    __shared__ float bparr[512];
    __shared__ float bparrX[2][512];
    __shared__ float bpF2[2][128];
    const int t = threadIdx.x;
    const int lane = t & 63;
    const int wave = t >> 6;                 // 8 waves
    const int rowBase = blockIdx.x * 128 + wave * 16;
    const int m = lane & 15;
    const int kq = lane >> 4;
    constexpr int kbEnd = (MODEB == 0) ? 8 : 4;
    const int colW = t & 127;
    const int qs0 = t >> 7;                  // 0..3: each thread stages ONE shortx8
    const int bBlk = (blockIdx.x * 128) / rowsPerBatch;  // block spans <=2 batches
    const int arow = rowBase + m;

    // ---- per-block BN fold prologue (exact former fold_kernel arithmetic) ----
    if (t < 256) {
        int k = t;
        float mean, var;
        if (MODEB == 1 && k >= 128) {
            int c = k - 128;
            float a0 = avgacc[c] / msum[0];
            float a1 = avgacc[128 + c] / msum[1];
            float a2 = avgacc[256 + c] / msum[2];
            float a3 = avgacc[384 + c] / msum[3];
            avgLDS[c] = a0; avgLDS[128 + c] = a1;
            avgLDS[256 + c] = a2; avgLDS[384 + c] = a3;
            mean = 0.25f * (a0 + a1 + a2 + a3);
            var = 0.25f * (a0 * a0 + a1 * a1 + a2 * a2 + a3 * a3) - mean * mean;
        } else {
            mean = S[k] * invR;
            var = S[256 + k] * invR - mean * mean;
        }
        float s = gvec[k] / sqrtf(var + EPS);
        sS[k] = s;
        sMS[k] = bevec[k] - mean * s;
    }
    // first __syncthreads() of the kb loop guards sS/sMS/avgLDS.

    floatx4 acc[8];
#pragma unroll
    for (int j = 0; j < 8; ++j) acc[j] = {0.f, 0.f, 0.f, 0.f};

    float bpp = 0.f;  // per-thread bias-fold partial (col = t&127, qs = qs0)
    for (int kb = 0; kb < kbEnd; ++kb) {
        const int k0 = kb * 32 + kq * 8;
        __syncthreads();
        // ---- stage W tile: each thread folds ONE shortx8 (col=colW, qs=qs0) ----
        {
            shortx8 hv, lv;
#pragma unroll
            for (int j = 0; j < 8; ++j) {
                int k = kb * 32 + qs0 * 8 + j;
                float w = Wfull[(size_t)k * 128 + colW];
                float wp = sS[k] * w;
                short h = f2bf(wp);
                hv[j] = h;
                lv[j] = f2bf(wp - bf2f(h));
                bpp += sMS[k] * w;
            }
            *(shortx8*)&Bsh[colW * 40 + qs0 * 8] = hv;
            *(shortx8*)&Bsl[colW * 40 + qs0 * 8] = lv;
        }
        // ---- A frag for this wave's 16 rows ----
        shortx8 ah, al;
        {
            float4 p, q;
            if (kb < 4) {
                p = elu4(*(const float4*)&A[(size_t)arow * 128 + k0]);
                q = elu4(*(const float4*)&A[(size_t)arow * 128 + k0 + 4]);
            } else {  // only MODEB==0 reaches here
                int kk = k0 - 128;
                p = elu4(*(const float4*)&Bs[(size_t)arow * 128 + kk]);
                q = elu4(*(const float4*)&Bs[(size_t)arow * 128 + kk + 4]);
            }
            float x[8] = {p.x, p.y, p.z, p.w, q.x, q.y, q.z, q.w};
#pragma unroll
            for (int j = 0; j < 8; ++j) { short h, l; split2(x[j], h, l); ah[j] = h; al[j] = l; }
        }
        __syncthreads();
#pragma unroll
        for (int ct = 0; ct < 8; ++ct) {
            const int co = (ct * 16 + m) * 40 + kq * 8;
            shortx8 bh = *(const shortx8*)&Bsh[co];
            shortx8 bl = *(const shortx8*)&Bsl[co];
            acc[ct] = __builtin_amdgcn_mfma_f32_16x16x32_bf16(ah, bh, acc[ct], 0, 0, 0);
            acc[ct] = __builtin_amdgcn_mfma_f32_16x16x32_bf16(ah, bl, acc[ct], 0, 0, 0);
            acc[ct] = __builtin_amdgcn_mfma_f32_16x16x32_bf16(al, bh, acc[ct], 0, 0, 0);
        }
    }

    // ---- bias for skipped k>=128 ----
    float bps0 = 0.f, bps1 = 0.f;   // per-spanned-batch extras
    if (MODEB == 2) {
        // B input is identically 0: only the sMS[k]*W term for k>=128.
        for (int j = 0; j < 32; ++j) {
            int k = 128 + qs0 * 32 + j;
            bps0 += sMS[k] * Wfull[(size_t)k * 128 + colW];
        }
        bps1 = bps0;
    } else if (MODEB == 1) {
        // B-half is a per-batch broadcast: fold into per-batch bias
        //   sum_k (sMS[k] + avg[b][k-128]*sS[k]) * W[k][col], fp32-exact.
        const int b0 = bBlk, b1 = (bBlk + 1 < 4) ? bBlk + 1 : 3;
        for (int j = 0; j < 32; ++j) {
            int k = 128 + qs0 * 32 + j;
            float w = Wfull[(size_t)k * 128 + colW];
            float sw = sS[k] * w;
            float base = sMS[k] * w;
            bps0 += base + avgLDS[b0 * 128 + (k - 128)] * sw;
            bps1 += base + avgLDS[b1 * 128 + (k - 128)] * sw;
        }
    }
    // ---- finish bias fold (4 threads share col = t&127) ----
    bparr[t] = bpp;
    bparrX[0][t] = bps0;
    bparrX[1][t] = bps1;
    __syncthreads();
    if (t < 128) {
        float common = bvec[t] + bparr[t] + bparr[t + 128] + bparr[t + 256] + bparr[t + 384];
        bpF2[0][t] = common + bparrX[0][t] + bparrX[0][t + 128] + bparrX[0][t + 256] + bparrX[0][t + 384];
        bpF2[1][t] = common + bparrX[1][t] + bparrX[1][t + 128] + bparrX[1][t + 256] + bparrX[1][t + 384];
    }
    __syncthreads();

    // epilogue: C/D layout col=lane&15, row=(lane>>4)*4+reg  [verified m89/m91]
    float mk4[4]; int ib4[4];
#pragma unroll
    for (int r = 0; r < 4; ++r) {
        int row = rowBase + kq * 4 + r;
        ib4[r] = (row >= (bBlk + 1) * rowsPerBatch) ? 1 : 0;
        if (avgout) mk4[r] = mask[row];
    }
    float cs1[8], cs2[8], av0[8], av1[8];
#pragma unroll
    for (int ct = 0; ct < 8; ++ct) { cs1[ct] = 0.f; cs2[ct] = 0.f; av0[ct] = 0.f; av1[ct] = 0.f; }
#pragma unroll
    for (int ct = 0; ct < 8; ++ct) {
        int col = ct * 16 + m;
        float bb0 = bpF2[0][col], bb1 = bpF2[1][col];
#pragma unroll
        for (int r = 0; r < 4; ++r) {
            int row = rowBase + kq * 4 + r;
            size_t o = (size_t)row * 128 + col;
            float v = acc[ct][r] + (ib4[r] ? bb1 : bb0);
            if (resid) v += resid[o];
            out[o] = v;
            if (shadow) {
                int b = row / rowsPerBatch, vert = row - b * rowsPerBatch;
                shadow[(size_t)(4 * vert + (col >> 5)) * 128 + b * 32 + (col & 31)] =
                    __float2half(v);
            }
            float e = eluf(v);
            cs1[ct] += e; cs2[ct] += e * e;
            if (avgout) {
                float me = mk4[r] * e;
                if (ib4[r]) av1[ct] += me; else av0[ct] += me;
            }
        }
    }
    if (Sout) {  // fused stats (+ optional avg numerators) for the consuming layer
        __syncthreads();
        float* red = (float*)Bsh;
        float* redv = (float*)Bsl;
        if (t < 256) {
            red[t] = 0.f;
            if (avgout) redv[t] = 0.f;
        }
        __syncthreads();
#pragma unroll
        for (int ct = 0; ct < 8; ++ct) {
            cs1[ct] += __shfl_xor(cs1[ct], 16); cs1[ct] += __shfl_xor(cs1[ct], 32);
            cs2[ct] += __shfl_xor(cs2[ct], 16); cs2[ct] += __shfl_xor(cs2[ct], 32);
            if (avgout) {
                av0[ct] += __shfl_xor(av0[ct], 16); av0[ct] += __shfl_xor(av0[ct], 32);
                av1[ct] += __shfl_xor(av1[ct], 16); av1[ct] += __shfl_xor(av1[ct], 32);
            }
        }
        if (kq == 0) {
#pragma unroll
            for (int ct = 0; ct < 8; ++ct) {
                atomicAdd(&red[ct * 16 + m], cs1[ct]);
                atomicAdd(&red[128 + ct * 16 + m], cs2[ct]);
                if (avgout) {
                    atomicAdd(&redv[ct * 16 + m], av0[ct]);
                    atomicAdd(&redv[128 + ct * 16 + m], av1[ct]);
                }
            }
        }
        __syncthreads();
        if (t < 128) atomicAdd(&Sout[t], red[t]);
        else if (t < 256) atomicAdd(&Sout[256 + (t - 128)], red[t]);
        if (avgout && t < 256) {
            int plane = t >> 7, col = t & 127;
            int b = bBlk + plane;
            if (b < 4) atomicAdd(&avgout[b * 128 + col], redv[t]);
        }
    }
}

__global__ void fold_final(const float* __restrict__ S, const float* __restrict__ g2,
                           const float* __restrict__ be2, const float* __restrict__ W2,
                           const float* __restrict__ b2, float* __restrict__ W2p, float invR) {
    __shared__ float red[128];
    int c = threadIdx.x;
    float mean = S[c] * invR;
    float var = S[256 + c] * invR - mean * mean;
    float s = g2[c] / sqrtf(var + EPS);
    float w = W2[c];
    W2p[c] = s * w;
    red[c] = (be2[c] - mean * s) * w;
    __syncthreads();
    for (int st = 64; st > 0; st >>= 1) {
        if (c < st) red[c] += red[c + st];
        __syncthreads();
    }
    if (c == 0) W2p[128] = b2[0] + red[0];
}

__global__ void final_out_kernel(const float* __restrict__ f, const float* __restrict__ W2p,
                                 float* __restrict__ out) {
    int t = threadIdx.x;
    int w = t >> 6, lane = t & 63;
    float wa = W2p[lane], wb = W2p[64 + lane], bb = W2p[128];
    int base = blockIdx.x * 16 + w * 4;
#pragma unroll
    for (int rr = 0; rr < 4; ++rr) {
        int row = base + rr;
        float a = eluf(f[(size_t)row * 128 + lane]) * wa +
                  eluf(f[(size_t)row * 128 + 64 + lane]) * wb;
        for (int off = 32; off > 0; off >>= 1) a += __shfl_down(a, off);
        if (lane == 0) out[row] = a + bb;
    }
}

extern "C" void kernel_launch(void* const* d_in, const int* in_sizes, int n_in,
                              void* d_out, int out_size, void* d_ws, size_t ws_size,
                              hipStream_t stream) {
    const float* inputs = (const float*)d_in[0];
    const float* mask = (const float*)d_in[1];
    const int* Di_rows = (const int*)d_in[2];
    const int* Di_cols = (const int*)d_in[3];
    const float* Di_vals = (const float*)d_in[4];
    const int* DiA_rows = (const int*)d_in[5];
    const int* DiA_cols = (const int*)d_in[6];
    const float* DiA_vals = (const float*)d_in[7];
    const float* W1 = (const float*)d_in[8];
    const float* b1 = (const float*)d_in[9];
    const float* rn_gamma = (const float*)d_in[10];
    const float* rn_beta = (const float*)d_in[11];
    const float* rn_W = (const float*)d_in[12];
    const float* rn_b = (const float*)d_in[13];
    const float* g2 = (const float*)d_in[14];
    const float* be2 = (const float*)d_in[15];
    const float* W2 = (const float*)d_in[16];
    const float* b2 = (const float*)d_in[17];
    float* out = (float*)d_out;

    const int B = 4;
    const int BN = in_sizes[1];      // 48000
    const int N = BN / B;            // 12000
    const int BF = out_size;         // 96000
    const int Fn = BF / B;           // 24000
    const int nnz = in_sizes[2];     // 1,152,000
    const int RA = 4 * N;            // 48000
    const int RD = 4 * Fn;           // 96000

    float* ws = (float*)d_ws;
    size_t off = 0;
    float* vA = ws + off;  off += (size_t)BN * 128;
    float* fA = ws + off;  off += (size_t)BF * 128;
    float* msg = ws + off; off += (size_t)BF * 128;   // fp32 spmm out
    __half* vH = (__half*)(ws + off); off += (size_t)RA * 128 / 2;  // [r4][b][32] fp16
    __half* fH = (__half*)(ws + off); off += (size_t)RD * 128 / 2;
    int* ptrA    = (int*)(ws + off);  off += (size_t)RA + 4;
    int2* edgesA = (int2*)(ws + off); off += (size_t)nnz * 2;
    int* ptrD    = (int*)(ws + off);  off += (size_t)RD + 4;
    int2* edgesD = (int2*)(ws + off); off += (size_t)nnz * 2;
    int* cntA    = (int*)(ws + off);  off += (size_t)RA;
    int* cntD    = (int*)(ws + off);  off += (size_t)RD;
    int* partA   = (int*)(ws + off);  off += 256;
    int* partD   = (int*)(ws + off);  off += 256;
    float* Sarena = ws + off; off += 33 * 512;   // pre-zeroed stats slots (2i+j map)
    float* Aarena = ws + off; off += 16 * 512;   // pre-zeroed avg-numerator slots
    float* msum = ws + off;   off += 4;
    float* W2p = ws + off; off += 132;

    const int eBlocks = nnz / 256;
    const int PA = (RA + 1023) / 1024;
    const int PD = (RD + 1023) / 1024;

    hipMemsetAsync(Sarena, 0, (33 * 512 + 16 * 512) * 4, stream);
    hipMemsetAsync(fA, 0, (size_t)BF * 128 * 4, stream);
    hipMemsetAsync(cntA, 0, (size_t)(RA + RD) * 4, stream);  // cntA+cntD contiguous

    // ---- build CSR for DiA and Di in one merged chain ----
    hist2_kernel<<<dim3(eBlocks, 2), 256, 0, stream>>>(DiA_rows, Di_rows, cntA, cntD);
    partial2_kernel<<<dim3(PD, 2), 256, 0, stream>>>(cntA, cntD, partA, partD, RA, RD);
    scanp2_kernel<<<dim3(1, 2), 256, 0, stream>>>(partA, partD, ptrA, ptrD, PA, PD,
                                                  RA, RD, nnz);
    apply2_kernel<<<dim3(PD, 2), 256, 0, stream>>>(cntA, cntD, partA, partD, ptrA, ptrD,
                                                   RA, RD);
    scatter2_kernel<<<dim3(eBlocks, 2), 256, 0, stream>>>(DiA_rows, DiA_cols, DiA_vals,
                                                          Di_rows, Di_cols, Di_vals,
                                                          cntA, cntD, edgesA, edgesD);

    // S slot map: conv layer (i,j) -> Sarena + 512*(2i+j); final conv -> slot 32.
    auto slot = [&](int i, int j) { return Sarena + 512 * (2 * i + j); };
    float* Sfinal = Sarena + 512 * 32;

    // conv1 + masksum merged (last B blocks do masksum)
    conv1_kernel<<<BN / 64 + B, 256, 0, stream>>>(inputs, W1, b1, vA, vH, N, slot(0, 0),
                                                  mask, msum, BN / 64);

    for (int i = 0; i < 15; ++i) {   // layer 15 (avg) is dead: output depends only on f
        if ((i & 1) == 0) {
            const float* g0 = rn_gamma + (size_t)(i * 2 + 0) * 256;
            const float* be0 = rn_beta + (size_t)(i * 2 + 0) * 256;
            const float* Wl0 = rn_W + (size_t)(i * 2 + 0) * 256 * 128;
            const float* bl0 = rn_b + (size_t)(i * 2 + 0) * 128;
            const float* g1 = rn_gamma + (size_t)(i * 2 + 1) * 256;
            const float* be1 = rn_beta + (size_t)(i * 2 + 1) * 256;
            const float* Wl1 = rn_W + (size_t)(i * 2 + 1) * 256 * 128;
            const float* bl1 = rn_b + (size_t)(i * 2 + 1) * 128;
            float* SoutV = (i < 14) ? slot(i + 1, 0) : nullptr;
            float* avgV = (i < 14) ? (Aarena + 512 * i) : nullptr;

            if (i == 0) {
                // f == 0 -> msg_v == 0 exactly: skip spmm; slot(0,0) B-half stays 0.
                gemm_mfma<2><<<BN / 128, 512, 0, stream>>>(vA, nullptr, slot(0, 0), g0, be0,
                                                           Wl0, bl0, vA, vA, vH, SoutV, mask,
                                                           avgV, nullptr, nullptr, 1.f / BN,
                                                           N);
            } else {
                spmm_csr_kernel<0><<<RA / 32, 1024, 0, stream>>>(ptrA, edgesA,
                                                                 (const __half2*)fH, msg,
                                                                 RA, slot(i, 0));
                gemm_mfma<0><<<BN / 128, 512, 0, stream>>>(vA, msg, slot(i, 0), g0, be0,
                                                           Wl0, bl0, vA, vA, vH, SoutV, mask,
                                                           avgV, nullptr, nullptr, 1.f / BN,
                                                           N);
            }

            spmm_csr_kernel<1><<<RD / 32, 1024, 0, stream>>>(ptrD, edgesD,
                                                             (const __half2*)vH, msg, RD,
                                                             slot(i, 1));
            gemm_mfma<0><<<BF / 128, 512, 0, stream>>>(fA, msg, slot(i, 1), g1, be1, Wl1,
                                                       bl1, nullptr, fA, fH,
                                                       (i < 14) ? slot(i + 2, 1) : Sfinal,
                                                       nullptr, nullptr, nullptr, nullptr,
                                                       1.f / BF, Fn);
        } else {
            for (int j = 0; j < 2; ++j) {
                const float* g = rn_gamma + (size_t)(i * 2 + j) * 256;
                const float* be = rn_beta + (size_t)(i * 2 + j) * 256;
                const float* Wlw = rn_W + (size_t)(i * 2 + j) * 256 * 128;
                const float* bl = rn_b + (size_t)(i * 2 + j) * 128;
                const float* src = (j == 0) ? vA : msg;
                float* dst = (j == 0) ? msg : vA;
                const float* resid = (j == 0) ? nullptr : vA;
                __half* shadow = (j == 0) ? nullptr : vH;
                float* SoutP = (j == 0) ? slot(i, 1) : slot(i + 1, 0);
                float* avgO = (j == 0) ? (Aarena + 512 * i) : nullptr;
                const float* avgacc = Aarena + 512 * (i - 1 + j);

                gemm_mfma<1><<<BN / 128, 512, 0, stream>>>(src, nullptr, slot(i, j), g, be,
                                                           Wlw, bl, resid, dst, shadow,
                                                           SoutP, mask, avgO, avgacc, msum,
                                                           1.f / BN, N);
            }
        }
    }

    fold_final<<<1, 128, 0, stream>>>(Sfinal, g2, be2, W2, b2, W2p, 1.f / BF);
    final_out_kernel<<<BF / 16, 256, 0, stream>>>(fA, W2p, out);
}